// Round 3
// baseline (276.103 us; speedup 1.0000x reference)
//
#include <hip/hip_runtime.h>

// EdgeModel: out = leaky_relu(concat(x_s[src], x_t[tgt], edge_attr, u[batch]) @ W1 + b1) @ W2 + b2
// F_XS=10, F_XT=5, F_E=10, F_U=10 -> concat 35, hidden 10, out 10.
//
// Round 3 (= round 2 with compile fix): transaction-bound fix.
//  - 2 edges/thread: edge_attr & out become 16B-aligned float4 streams (80 B per thread).
//  - Gathers widened: 10-float row = dwordx4+dwordx4+dwordx2 (3 insts vs 5),
//    5-float row = dwordx4+dword (2 insts vs 5).
//  - Non-temporal streaming loads/stores (via native ext_vector float4 — the HIP
//    float4 struct is rejected by __builtin_nontemporal_*) so edge_attr/out don't
//    evict the gather tables (x_s = 4 MB = one XCD L2) from L2.

#define F_XS 10
#define F_XT 5
#define F_E  10
#define F_U  10
#define F_IN 35

typedef float vf4 __attribute__((ext_vector_type(4)));  // native vector: OK for nontemporal builtins
union F4 { vf4 v; float f[4]; };

__device__ __forceinline__ void gather10(const float* __restrict__ p, float* __restrict__ dst) {
    // row is 8-byte aligned (40 B stride); dwordx4 at dword alignment is HW-supported
    float4 a = *(const float4*)(p);
    float4 b = *(const float4*)(p + 4);
    float2 c = *(const float2*)(p + 8);
    dst[0]=a.x; dst[1]=a.y; dst[2]=a.z; dst[3]=a.w;
    dst[4]=b.x; dst[5]=b.y; dst[6]=b.z; dst[7]=b.w;
    dst[8]=c.x; dst[9]=c.y;
}

__device__ __forceinline__ void gather5(const float* __restrict__ p, float* __restrict__ dst) {
    // row is 4-byte aligned (20 B stride)
    float4 a = *(const float4*)(p);
    dst[0]=a.x; dst[1]=a.y; dst[2]=a.z; dst[3]=a.w;
    dst[4]=p[4];
}

__device__ __forceinline__ void mlp(const float* __restrict__ in,
                                    const float* __restrict__ W1, const float* __restrict__ b1,
                                    const float* __restrict__ W2, const float* __restrict__ b2,
                                    float* __restrict__ o) {
    float h[F_E];
    #pragma unroll
    for (int j = 0; j < F_E; ++j) h[j] = b1[j];
    #pragma unroll
    for (int k = 0; k < F_IN; ++k) {
        const float a = in[k];
        #pragma unroll
        for (int j = 0; j < F_E; ++j) h[j] = fmaf(a, W1[k * F_E + j], h[j]);
    }
    #pragma unroll
    for (int j = 0; j < F_E; ++j) h[j] = (h[j] >= 0.0f) ? h[j] : 0.1f * h[j];

    #pragma unroll
    for (int j = 0; j < F_E; ++j) o[j] = b2[j];
    #pragma unroll
    for (int k = 0; k < F_E; ++k) {
        const float a = h[k];
        #pragma unroll
        for (int j = 0; j < F_E; ++j) o[j] = fmaf(a, W2[k * F_E + j], o[j]);
    }
}

__global__ __launch_bounds__(256) void edge_model_kernel(
    const float* __restrict__ x_s,        // [N_S, 10]
    const float* __restrict__ x_t,        // [N_T, 5]
    const int*   __restrict__ edge_index, // [2, E]
    const float* __restrict__ edge_attr,  // [E, 10]
    const float* __restrict__ u,          // [B, 10]
    const int*   __restrict__ batch_e,    // [E]
    const float* __restrict__ W1,         // [35, 10]
    const float* __restrict__ b1,         // [10]
    const float* __restrict__ W2,         // [10, 10]
    const float* __restrict__ b2,         // [10]
    float*       __restrict__ out,        // [E, 10]
    int E)
{
    const int t  = blockIdx.x * blockDim.x + threadIdx.x;
    const int e0 = 2 * t;
    if (e0 >= E) return;
    const bool two = (e0 + 1) < E;   // E=2M is even; guard anyway

    // index loads: e0 even, E even -> all int2 loads are 8B-aligned, coalesced
    const int2 sp = *(const int2*)(edge_index + e0);
    const int2 tp = *(const int2*)(edge_index + E + e0);
    const int2 bp = *(const int2*)(batch_e + e0);

    float in0[F_IN], in1[F_IN];

    gather10(x_s + (long long)sp.x * F_XS, in0);
    gather5 (x_t + (long long)tp.x * F_XT, in0 + 10);
    gather10(u   + (long long)bp.x * F_U,  in0 + 25);
    if (two) {
        gather10(x_s + (long long)sp.y * F_XS, in1);
        gather5 (x_t + (long long)tp.y * F_XT, in1 + 10);
        gather10(u   + (long long)bp.y * F_U,  in1 + 25);
    }

    // edge_attr: 2 rows = 80 B starting at byte offset 80*t -> 16B-aligned float4 x5
    {
        const vf4* p = (const vf4*)(edge_attr + (long long)e0 * F_E);
        F4 q[5];
        if (two) {
            #pragma unroll
            for (int i = 0; i < 5; ++i) q[i].v = __builtin_nontemporal_load(p + i);
        } else {
            const float* ps = (const float*)p;
            #pragma unroll
            for (int i = 0; i < 10; ++i) ((float*)q)[i] = ps[i];
        }
        const float* qs = (const float*)q;
        #pragma unroll
        for (int i = 0; i < 10; ++i) { in0[15 + i] = qs[i]; }
        if (two) {
            #pragma unroll
            for (int i = 0; i < 10; ++i) { in1[15 + i] = qs[10 + i]; }
        }
    }

    float o0[F_E], o1[F_E];
    mlp(in0, W1, b1, W2, b2, o0);
    if (two) mlp(in1, W1, b1, W2, b2, o1);

    // out: 80 B at byte offset 80*t -> 16B-aligned float4 x5, non-temporal
    if (two) {
        F4 r[5];
        float* rs = (float*)r;
        #pragma unroll
        for (int i = 0; i < 10; ++i) { rs[i] = o0[i]; rs[10 + i] = o1[i]; }
        vf4* po = (vf4*)(out + (long long)e0 * F_E);
        #pragma unroll
        for (int i = 0; i < 5; ++i) __builtin_nontemporal_store(r[i].v, po + i);
    } else {
        float* po = out + (long long)e0 * F_E;
        #pragma unroll
        for (int i = 0; i < 10; ++i) po[i] = o0[i];
    }
}

extern "C" void kernel_launch(void* const* d_in, const int* in_sizes, int n_in,
                              void* d_out, int out_size, void* d_ws, size_t ws_size,
                              hipStream_t stream) {
    const float* x_s        = (const float*)d_in[0];
    const float* x_t        = (const float*)d_in[1];
    const int*   edge_index = (const int*)  d_in[2];
    const float* edge_attr  = (const float*)d_in[3];
    const float* u          = (const float*)d_in[4];
    const int*   batch_e    = (const int*)  d_in[5];
    const float* W1         = (const float*)d_in[6];
    const float* b1         = (const float*)d_in[7];
    const float* W2         = (const float*)d_in[8];
    const float* b2         = (const float*)d_in[9];
    float*       out        = (float*)d_out;

    const int E = in_sizes[5];  // batch_e is [E]
    const int nthreads = (E + 1) / 2;
    const int block = 256;
    const int grid  = (nthreads + block - 1) / block;

    edge_model_kernel<<<grid, block, 0, stream>>>(
        x_s, x_t, edge_index, edge_attr, u, batch_e, W1, b1, W2, b2, out, E);
}

// Round 4
// 244.185 us; speedup vs baseline: 1.1307x; 1.1307x over previous
//
#include <hip/hip_runtime.h>

// EdgeModel: out = leaky_relu(concat(x_s[src], x_t[tgt], edge_attr, u[batch]) @ W1 + b1) @ W2 + b2
// F_XS=10, F_XT=5, F_E=10, F_U=10 -> concat 35, hidden 10, out 10.
//
// Round 4: revert round-3 regressions, keep its wins.
//  - 1 edge/thread (round 3's 2-edge version spilled: VGPR 64, VALU 5x, occupancy 37%).
//  - Wide gathers kept: 10-float row = dwordx4+dwordx4+dwordx2, 5-float = dwordx4+dword
//    (HW needs only dword alignment for multi-dword global loads).
//  - Non-temporal LOADS kept for all streaming inputs (edge_attr, edge_index, batch_e):
//    round 3 showed FETCH 213->192 MB (tables stay L2-resident).
//  - PLAIN stores (round 3's NT stores doubled HBM write bytes: 79->151 MB —
//    nt bypasses L2 write-combining -> partial-line HBM bursts).
//  - Segment-wise accumulation into h so each input segment's registers retire
//    right after its vmcnt arrives (keeps VGPR low, overlaps FMA with gathers).

#define F_XS 10
#define F_XT 5
#define F_E  10
#define F_U  10
#define F_IN 35

typedef float vf4 __attribute__((ext_vector_type(4)));
typedef float vf2 __attribute__((ext_vector_type(2)));

__global__ __launch_bounds__(256) void edge_model_kernel(
    const float* __restrict__ x_s,        // [N_S, 10]
    const float* __restrict__ x_t,        // [N_T, 5]
    const int*   __restrict__ edge_index, // [2, E]
    const float* __restrict__ edge_attr,  // [E, 10]
    const float* __restrict__ u,          // [B, 10]
    const int*   __restrict__ batch_e,    // [E]
    const float* __restrict__ W1,         // [35, 10]
    const float* __restrict__ b1,         // [10]
    const float* __restrict__ W2,         // [10, 10]
    const float* __restrict__ b2,         // [10]
    float*       __restrict__ out,        // [E, 10]
    int E)
{
    const int e = blockIdx.x * blockDim.x + threadIdx.x;
    if (e >= E) return;

    // streaming index loads, non-temporal
    const int src = __builtin_nontemporal_load(edge_index + e);
    const int tgt = __builtin_nontemporal_load(edge_index + E + e);
    const int be  = __builtin_nontemporal_load(batch_e + e);

    // ---- issue all loads up front (compiler schedules, fine-grained vmcnt) ----
    const float* ps = x_s + (long long)src * F_XS;   // 8B-aligned 40 B row
    vf4 s0 = *(const vf4*)(ps);
    vf4 s1 = *(const vf4*)(ps + 4);
    vf2 s2 = *(const vf2*)(ps + 8);

    const float* pt = x_t + (long long)tgt * F_XT;   // 4B-aligned 20 B row
    vf4 t0 = *(const vf4*)(pt);
    float t1 = pt[4];

    const float* pe = edge_attr + (long long)e * F_E; // 8B-aligned, streaming -> NT
    vf4 a0 = __builtin_nontemporal_load((const vf4*)(pe));
    vf4 a1 = __builtin_nontemporal_load((const vf4*)(pe + 4));
    vf2 a2 = __builtin_nontemporal_load((const vf2*)(pe + 8));

    const float* pu = u + (long long)be * F_U;       // 8B-aligned 40 B row
    vf4 u0 = *(const vf4*)(pu);
    vf4 u1 = *(const vf4*)(pu + 4);
    vf2 u2 = *(const vf2*)(pu + 8);

    // ---- layer 1, segment-wise accumulation ----
    float h[F_E];
    #pragma unroll
    for (int j = 0; j < F_E; ++j) h[j] = b1[j];

    {   // x_s segment: k = 0..9
        float seg[10] = {s0.x,s0.y,s0.z,s0.w, s1.x,s1.y,s1.z,s1.w, s2.x,s2.y};
        #pragma unroll
        for (int k = 0; k < 10; ++k) {
            #pragma unroll
            for (int j = 0; j < F_E; ++j) h[j] = fmaf(seg[k], W1[k * F_E + j], h[j]);
        }
    }
    {   // x_t segment: k = 10..14
        float seg[5] = {t0.x,t0.y,t0.z,t0.w, t1};
        #pragma unroll
        for (int k = 0; k < 5; ++k) {
            #pragma unroll
            for (int j = 0; j < F_E; ++j) h[j] = fmaf(seg[k], W1[(10 + k) * F_E + j], h[j]);
        }
    }
    {   // edge_attr segment: k = 15..24
        float seg[10] = {a0.x,a0.y,a0.z,a0.w, a1.x,a1.y,a1.z,a1.w, a2.x,a2.y};
        #pragma unroll
        for (int k = 0; k < 10; ++k) {
            #pragma unroll
            for (int j = 0; j < F_E; ++j) h[j] = fmaf(seg[k], W1[(15 + k) * F_E + j], h[j]);
        }
    }
    {   // u segment: k = 25..34
        float seg[10] = {u0.x,u0.y,u0.z,u0.w, u1.x,u1.y,u1.z,u1.w, u2.x,u2.y};
        #pragma unroll
        for (int k = 0; k < 10; ++k) {
            #pragma unroll
            for (int j = 0; j < F_E; ++j) h[j] = fmaf(seg[k], W1[(25 + k) * F_E + j], h[j]);
        }
    }

    #pragma unroll
    for (int j = 0; j < F_E; ++j) h[j] = (h[j] >= 0.0f) ? h[j] : 0.1f * h[j];

    // ---- layer 2 ----
    float o[F_E];
    #pragma unroll
    for (int j = 0; j < F_E; ++j) o[j] = b2[j];
    #pragma unroll
    for (int k = 0; k < F_E; ++k) {
        const float a = h[k];
        #pragma unroll
        for (int j = 0; j < F_E; ++j) o[j] = fmaf(a, W2[k * F_E + j], o[j]);
    }

    // ---- store: plain wide stores (dwordx4+x4+x2), L2 write-combines to full lines ----
    float* po = out + (long long)e * F_E;
    vf4 w0; w0.x=o[0]; w0.y=o[1]; w0.z=o[2]; w0.w=o[3];
    vf4 w1; w1.x=o[4]; w1.y=o[5]; w1.z=o[6]; w1.w=o[7];
    vf2 w2; w2.x=o[8]; w2.y=o[9];
    *(vf4*)(po)     = w0;
    *(vf4*)(po + 4) = w1;
    *(vf2*)(po + 8) = w2;
}

extern "C" void kernel_launch(void* const* d_in, const int* in_sizes, int n_in,
                              void* d_out, int out_size, void* d_ws, size_t ws_size,
                              hipStream_t stream) {
    const float* x_s        = (const float*)d_in[0];
    const float* x_t        = (const float*)d_in[1];
    const int*   edge_index = (const int*)  d_in[2];
    const float* edge_attr  = (const float*)d_in[3];
    const float* u          = (const float*)d_in[4];
    const int*   batch_e    = (const int*)  d_in[5];
    const float* W1         = (const float*)d_in[6];
    const float* b1         = (const float*)d_in[7];
    const float* W2         = (const float*)d_in[8];
    const float* b2         = (const float*)d_in[9];
    float*       out        = (float*)d_out;

    const int E = in_sizes[5];  // batch_e is [E]
    const int block = 256;
    const int grid  = (E + block - 1) / block;

    edge_model_kernel<<<grid, block, 0, stream>>>(
        x_s, x_t, edge_index, edge_attr, u, batch_e, W1, b1, W2, b2, out, E);
}

// Round 5
// 239.005 us; speedup vs baseline: 1.1552x; 1.0217x over previous
//
#include <hip/hip_runtime.h>

// EdgeModel: out = leaky_relu(concat(x_s[src], x_t[tgt], edge_attr, u[batch]) @ W1 + b1) @ W2 + b2
// F_XS=10, F_XT=5, F_E=10, F_U=10 -> concat 35, hidden 10, out 10.
//
// Round 5: shrink the gather tables to f16 so they fit in one XCD's 4 MB L2.
//   Cross-round invariant: bytes/dur pinned at ~2.5-2.7 TB/s regardless of kernel
//   structure -> byte-bound. FETCH was 205 MB vs 104 MB streaming-ideal; the ~101 MB
//   delta is L2 thrash of the 6.4 MB f32 tables. f16 tables (3.4 MB total, built in
//   d_ws by a tiny per-call pass) fit in L2 -> steady-state gather refill ~0 and
//   gather latency drops to L2-hit.
//   - x_s: 10 f16 = 20 B rows (dwordx4+dword), u: same; x_t: padded to 6 f16 = 12 B
//     rows -> single dwordx4 gather (reads 4 B slack past row; +16 B region pad).
//   - NT loads on streams (edge_attr, idx) kept: keeps L2 free for tables.
//   - Plain wide stores kept (NT stores doubled WRITE in round 3).
//   - ws_size guard: falls back to round-4 f32 path if ws too small.

#define F_XS 10
#define F_XT 5
#define F_E  10
#define F_U  10
#define F_IN 35

typedef float vf4 __attribute__((ext_vector_type(4)));
typedef float vf2 __attribute__((ext_vector_type(2)));
typedef _Float16 f16;

// ---------------- table conversion pass (runs every call, ~3 us) ----------------
__global__ __launch_bounds__(256) void convert_tables_kernel(
    const float* __restrict__ xs, const float* __restrict__ xt, const float* __restrict__ uu,
    f16* __restrict__ xs_h, f16* __restrict__ xt_h, f16* __restrict__ u_h,
    int n_xs_elems, int n_u_elems, int n_t_rows)
{
    const int tid = blockIdx.x * blockDim.x + threadIdx.x;
    if (tid < n_xs_elems) {
        xs_h[tid] = (f16)xs[tid];
    } else if (tid < n_xs_elems + n_u_elems) {
        const int i = tid - n_xs_elems;
        u_h[i] = (f16)uu[i];
    } else {
        const int r = tid - n_xs_elems - n_u_elems;
        if (r < n_t_rows) {
            const float* p = xt + (long long)r * F_XT;
            f16* q = xt_h + (long long)r * 6;
            #pragma unroll
            for (int i = 0; i < 5; ++i) q[i] = (f16)p[i];
            q[5] = (f16)0.f;
        }
    }
}

// ---------------- main kernel, f16 tables ----------------
__global__ __launch_bounds__(256) void edge_model_f16tab_kernel(
    const f16*   __restrict__ xs_h,       // [N_S, 10] f16
    const f16*   __restrict__ xt_h,       // [N_T, 6]  f16 (padded)
    const int*   __restrict__ edge_index, // [2, E]
    const float* __restrict__ edge_attr,  // [E, 10]
    const f16*   __restrict__ u_h,        // [B, 10] f16
    const int*   __restrict__ batch_e,    // [E]
    const float* __restrict__ W1,         // [35, 10]
    const float* __restrict__ b1,         // [10]
    const float* __restrict__ W2,         // [10, 10]
    const float* __restrict__ b2,         // [10]
    float*       __restrict__ out,        // [E, 10]
    int E)
{
    const int e = blockIdx.x * blockDim.x + threadIdx.x;
    if (e >= E) return;

    // streaming index loads, non-temporal
    const int src = __builtin_nontemporal_load(edge_index + e);
    const int tgt = __builtin_nontemporal_load(edge_index + E + e);
    const int be  = __builtin_nontemporal_load(batch_e + e);

    // ---- gathers: L2-resident f16 tables ----
    f16 s[10];  __builtin_memcpy(s, xs_h + (long long)src * 10, 20);  // dwordx4+dword
    f16 t[8];   __builtin_memcpy(t, xt_h + (long long)tgt * 6, 16);   // single dwordx4 (4B slack)
    f16 uv[10]; __builtin_memcpy(uv, u_h + (long long)be * 10, 20);   // dwordx4+dword

    // edge_attr: streaming -> NT wide loads
    const float* pe = edge_attr + (long long)e * F_E;
    vf4 a0 = __builtin_nontemporal_load((const vf4*)(pe));
    vf4 a1 = __builtin_nontemporal_load((const vf4*)(pe + 4));
    vf2 a2 = __builtin_nontemporal_load((const vf2*)(pe + 8));

    // ---- layer 1, segment-wise accumulation ----
    float h[F_E];
    #pragma unroll
    for (int j = 0; j < F_E; ++j) h[j] = b1[j];

    #pragma unroll
    for (int k = 0; k < 10; ++k) {          // x_s segment, k = 0..9
        const float a = (float)s[k];
        #pragma unroll
        for (int j = 0; j < F_E; ++j) h[j] = fmaf(a, W1[k * F_E + j], h[j]);
    }
    #pragma unroll
    for (int k = 0; k < 5; ++k) {           // x_t segment, k = 10..14
        const float a = (float)t[k];
        #pragma unroll
        for (int j = 0; j < F_E; ++j) h[j] = fmaf(a, W1[(10 + k) * F_E + j], h[j]);
    }
    {                                        // edge_attr segment, k = 15..24
        float seg[10] = {a0.x,a0.y,a0.z,a0.w, a1.x,a1.y,a1.z,a1.w, a2.x,a2.y};
        #pragma unroll
        for (int k = 0; k < 10; ++k) {
            #pragma unroll
            for (int j = 0; j < F_E; ++j) h[j] = fmaf(seg[k], W1[(15 + k) * F_E + j], h[j]);
        }
    }
    #pragma unroll
    for (int k = 0; k < 10; ++k) {          // u segment, k = 25..34
        const float a = (float)uv[k];
        #pragma unroll
        for (int j = 0; j < F_E; ++j) h[j] = fmaf(a, W1[(25 + k) * F_E + j], h[j]);
    }

    #pragma unroll
    for (int j = 0; j < F_E; ++j) h[j] = (h[j] >= 0.0f) ? h[j] : 0.1f * h[j];

    // ---- layer 2 ----
    float o[F_E];
    #pragma unroll
    for (int j = 0; j < F_E; ++j) o[j] = b2[j];
    #pragma unroll
    for (int k = 0; k < F_E; ++k) {
        const float a = h[k];
        #pragma unroll
        for (int j = 0; j < F_E; ++j) o[j] = fmaf(a, W2[k * F_E + j], o[j]);
    }

    // ---- plain wide stores (L2 write-combines full lines) ----
    float* po = out + (long long)e * F_E;
    vf4 w0; w0.x=o[0]; w0.y=o[1]; w0.z=o[2]; w0.w=o[3];
    vf4 w1; w1.x=o[4]; w1.y=o[5]; w1.z=o[6]; w1.w=o[7];
    vf2 w2; w2.x=o[8]; w2.y=o[9];
    *(vf4*)(po)     = w0;
    *(vf4*)(po + 4) = w1;
    *(vf2*)(po + 8) = w2;
}

// ---------------- fallback: round-4 f32 path (if ws too small) ----------------
__global__ __launch_bounds__(256) void edge_model_f32_kernel(
    const float* __restrict__ x_s, const float* __restrict__ x_t,
    const int*   __restrict__ edge_index, const float* __restrict__ edge_attr,
    const float* __restrict__ u, const int* __restrict__ batch_e,
    const float* __restrict__ W1, const float* __restrict__ b1,
    const float* __restrict__ W2, const float* __restrict__ b2,
    float* __restrict__ out, int E)
{
    const int e = blockIdx.x * blockDim.x + threadIdx.x;
    if (e >= E) return;
    const int src = __builtin_nontemporal_load(edge_index + e);
    const int tgt = __builtin_nontemporal_load(edge_index + E + e);
    const int be  = __builtin_nontemporal_load(batch_e + e);

    float in[F_IN];
    __builtin_memcpy(in,      x_s + (long long)src * F_XS, 40);
    __builtin_memcpy(in + 10, x_t + (long long)tgt * F_XT, 20);
    const float* pe = edge_attr + (long long)e * F_E;
    vf4 a0 = __builtin_nontemporal_load((const vf4*)(pe));
    vf4 a1 = __builtin_nontemporal_load((const vf4*)(pe + 4));
    vf2 a2 = __builtin_nontemporal_load((const vf2*)(pe + 8));
    in[15]=a0.x; in[16]=a0.y; in[17]=a0.z; in[18]=a0.w;
    in[19]=a1.x; in[20]=a1.y; in[21]=a1.z; in[22]=a1.w;
    in[23]=a2.x; in[24]=a2.y;
    __builtin_memcpy(in + 25, u + (long long)be * F_U, 40);

    float h[F_E];
    #pragma unroll
    for (int j = 0; j < F_E; ++j) h[j] = b1[j];
    #pragma unroll
    for (int k = 0; k < F_IN; ++k) {
        const float a = in[k];
        #pragma unroll
        for (int j = 0; j < F_E; ++j) h[j] = fmaf(a, W1[k * F_E + j], h[j]);
    }
    #pragma unroll
    for (int j = 0; j < F_E; ++j) h[j] = (h[j] >= 0.0f) ? h[j] : 0.1f * h[j];

    float o[F_E];
    #pragma unroll
    for (int j = 0; j < F_E; ++j) o[j] = b2[j];
    #pragma unroll
    for (int k = 0; k < F_E; ++k) {
        const float a = h[k];
        #pragma unroll
        for (int j = 0; j < F_E; ++j) o[j] = fmaf(a, W2[k * F_E + j], o[j]);
    }
    float* po = out + (long long)e * F_E;
    vf4 w0; w0.x=o[0]; w0.y=o[1]; w0.z=o[2]; w0.w=o[3];
    vf4 w1; w1.x=o[4]; w1.y=o[5]; w1.z=o[6]; w1.w=o[7];
    vf2 w2; w2.x=o[8]; w2.y=o[9];
    *(vf4*)(po)     = w0;
    *(vf4*)(po + 4) = w1;
    *(vf2*)(po + 8) = w2;
}

extern "C" void kernel_launch(void* const* d_in, const int* in_sizes, int n_in,
                              void* d_out, int out_size, void* d_ws, size_t ws_size,
                              hipStream_t stream) {
    const float* x_s        = (const float*)d_in[0];
    const float* x_t        = (const float*)d_in[1];
    const int*   edge_index = (const int*)  d_in[2];
    const float* edge_attr  = (const float*)d_in[3];
    const float* u          = (const float*)d_in[4];
    const int*   batch_e    = (const int*)  d_in[5];
    const float* W1         = (const float*)d_in[6];
    const float* b1         = (const float*)d_in[7];
    const float* W2         = (const float*)d_in[8];
    const float* b2         = (const float*)d_in[9];
    float*       out        = (float*)d_out;

    const int E   = in_sizes[5];           // batch_e is [E]
    const int N_S = in_sizes[0] / F_XS;
    const int N_T = in_sizes[1] / F_XT;
    const int Bn  = in_sizes[4] / F_U;

    // ws layout (16B-aligned regions): xs_h [N_S*10 f16] | xt_h [N_T*6 f16 + 16B slack] | u_h [Bn*10 f16]
    const size_t xs_bytes = (size_t)N_S * 10 * sizeof(f16);
    const size_t xs_off   = 0;
    const size_t xt_off   = (xs_off + xs_bytes + 15) & ~(size_t)15;
    const size_t xt_bytes = (size_t)N_T * 6 * sizeof(f16) + 16;  // +16: dwordx4 slack on last row
    const size_t u_off    = (xt_off + xt_bytes + 15) & ~(size_t)15;
    const size_t u_bytes  = (size_t)Bn * 10 * sizeof(f16);
    const size_t need     = u_off + u_bytes;

    const int block = 256;
    const int grid_e = (E + block - 1) / block;

    if (ws_size >= need) {
        f16* xs_h = (f16*)((char*)d_ws + xs_off);
        f16* xt_h = (f16*)((char*)d_ws + xt_off);
        f16* u_h  = (f16*)((char*)d_ws + u_off);

        const int n_xs = N_S * 10, n_u = Bn * 10;
        const int conv_threads = n_xs + n_u + N_T;
        convert_tables_kernel<<<(conv_threads + block - 1) / block, block, 0, stream>>>(
            x_s, x_t, u, xs_h, xt_h, u_h, n_xs, n_u, N_T);

        edge_model_f16tab_kernel<<<grid_e, block, 0, stream>>>(
            xs_h, xt_h, edge_index, edge_attr, u_h, batch_e, W1, b1, W2, b2, out, E);
    } else {
        edge_model_f32_kernel<<<grid_e, block, 0, stream>>>(
            x_s, x_t, edge_index, edge_attr, u, batch_e, W1, b1, W2, b2, out, E);
    }
}